// Round 6
// baseline (201.506 us; speedup 1.0000x reference)
//
#include <hip/hip_runtime.h>

#define SDIM 14
#define L_COORD 5.0f
#define L_NOOBJ 0.5f
#define BATCH 4096
#define CELLS (BATCH * SDIM * SDIM)   // 802816
#define BLOCK 256
#define NBLOCKS (CELLS / BLOCK)       // 3136
#define CELL_F 30
#define BLK_F (BLOCK * CELL_F)        // 7680 floats per tensor per block
#define BLK_F4 (BLK_F / 4)            // 1920 float4 per tensor per block

typedef float f4v __attribute__((ext_vector_type(4)));

// Round-5 structure with ONE change: split the two tensors across the two
// memory request paths. pred -> non-temporal (HBM streaming path, measured
// ~3.3 TB/s cap in R4/R5); targ -> ordinary cached loads (L3-resident after
// warm-up; cached path measured ~2.6 TB/s cap in R0-R3). If the caps are
// path-local, the flows overlap: 96.3MB/3.3 || 96.3MB/2.6 => ~37-42 us vs 58.
// The j==7 split is wave-uniform (waves 0-1 pred, waves 2-3 targ): no diverg.
__global__ __launch_bounds__(BLOCK) void yolo_partial(
    const float* __restrict__ pred, const float* __restrict__ targ,
    float* __restrict__ partial) {
    // 60 KB LDS: [0, BLK_F) = pred cells, [BLK_F, 2*BLK_F) = targ cells
    __shared__ float s[2 * BLK_F];

    const size_t base = (size_t)blockIdx.x * BLK_F;
    const f4v* pP = reinterpret_cast<const f4v*>(pred + base);
    const f4v* pT = reinterpret_cast<const f4v*>(targ + base);
    f4v v[15];
    // j = 0..6: idx = tid + j*256 <= 1791 < 1920  -> always pred (nt)
#pragma unroll
    for (int j = 0; j < 7; ++j)
        v[j] = __builtin_nontemporal_load(pP + threadIdx.x + j * BLOCK);
    // j = 7: idx = 1792..2047 straddles the pred/targ boundary at 1920.
    // tid < 128 (waves 0,1) -> pred nt; tid >= 128 (waves 2,3) -> targ cached.
    {
        const int idx = threadIdx.x + 7 * BLOCK;
        if (idx < BLK_F4) v[7] = __builtin_nontemporal_load(pP + idx);
        else              v[7] = *(pT + (idx - BLK_F4));
    }
    // j = 8..14: idx >= 2048 -> always targ (cached / L3-resident)
#pragma unroll
    for (int j = 8; j < 15; ++j)
        v[j] = *(pT + (threadIdx.x + j * BLOCK - BLK_F4));

    f4v* s4 = reinterpret_cast<f4v*>(s);
#pragma unroll
    for (int j = 0; j < 15; ++j)
        s4[threadIdx.x + j * BLOCK] = v[j];
    __syncthreads();

    // ---- per-cell compute from LDS (verbatim rounds 0/5: absmax was 0) ----
    const float* Pc = s + threadIdx.x * CELL_F;
    const float* Tc = s + BLK_F + threadIdx.x * CELL_F;

    float loss;
    if (Tc[4] > 0.0f) {
        // class loss (channels 10..29)
        float cls = 0.0f;
#pragma unroll
        for (int c = 10; c < 30; ++c) { float d = Pc[c] - Tc[c]; cls += d * d; }

        const float invS = 1.0f / (float)SDIM;
        const float t1x = Tc[0] * invS - Tc[2] * 0.5f;
        const float t1y = Tc[1] * invS - Tc[3] * 0.5f;
        const float t2x = Tc[0] * invS + Tc[2] * 0.5f;
        const float t2y = Tc[1] * invS + Tc[3] * 0.5f;
        const float area_t = (t2x - t1x) * (t2y - t1y);

        float iou0 = 0.0f, iou1 = 0.0f;
#pragma unroll
        for (int k = 0; k < 2; ++k) {
            const float bx = Pc[5 * k + 0], by = Pc[5 * k + 1];
            const float bw = Pc[5 * k + 2], bh = Pc[5 * k + 3];
            const float p1x = bx * invS - bw * 0.5f;
            const float p1y = by * invS - bh * 0.5f;
            const float p2x = bx * invS + bw * 0.5f;
            const float p2y = by * invS + bh * 0.5f;
            const float ltx = fmaxf(p1x, t1x), lty = fmaxf(p1y, t1y);
            const float rbx = fminf(p2x, t2x), rby = fminf(p2y, t2y);
            const float wx = fmaxf(rbx - ltx, 0.0f);
            const float wy = fmaxf(rby - lty, 0.0f);
            const float inter = wx * wy;
            const float area_p = (p2x - p1x) * (p2y - p1y);
            const float v2 = inter / (area_p + area_t - inter);
            if (k == 0) iou0 = v2; else iou1 = v2;
        }

        const bool pick1 = (iou0 <= iou1);
        const float iou_best = pick1 ? iou1 : iou0;
        const float psx = pick1 ? Pc[5] : Pc[0];
        const float psy = pick1 ? Pc[6] : Pc[1];
        const float psw = pick1 ? Pc[7] : Pc[2];
        const float psh = pick1 ? Pc[8] : Pc[3];
        const float psc = pick1 ? Pc[9] : Pc[4];
        const float tsx = pick1 ? Tc[5] : Tc[0];
        const float tsy = pick1 ? Tc[6] : Tc[1];
        const float tsw = pick1 ? Tc[7] : Tc[2];
        const float tsh = pick1 ? Tc[8] : Tc[3];

        const float dx = psx - tsx, dy = psy - tsy;
        const float dw = sqrtf(psw) - sqrtf(tsw);
        const float dh = sqrtf(psh) - sqrtf(tsh);
        const float reg = dx * dx + dy * dy + dw * dw + dh * dh;
        const float dconf = psc - iou_best;
        loss = cls + L_COORD * reg + dconf * dconf;
    } else {
        const float d4 = Pc[4] - Tc[4];
        const float d9 = Pc[9] - Tc[9];
        loss = L_NOOBJ * (d4 * d4 + d9 * d9);
    }

    // ---- wave (64-lane) shuffle reduction ----
#pragma unroll
    for (int off = 32; off > 0; off >>= 1)
        loss += __shfl_down(loss, off, 64);

    __shared__ float wsum[BLOCK / 64];
    const int lane = threadIdx.x & 63;
    const int wave = threadIdx.x >> 6;
    if (lane == 0) wsum[wave] = loss;
    __syncthreads();
    if (threadIdx.x == 0)
        partial[blockIdx.x] = wsum[0] + wsum[1] + wsum[2] + wsum[3];
}

__global__ __launch_bounds__(BLOCK) void yolo_final(
    const float* __restrict__ partial, float* __restrict__ out) {
    float s = 0.0f;
    for (int i = threadIdx.x; i < NBLOCKS; i += BLOCK) s += partial[i];
#pragma unroll
    for (int off = 32; off > 0; off >>= 1)
        s += __shfl_down(s, off, 64);
    __shared__ float wsum[BLOCK / 64];
    const int lane = threadIdx.x & 63;
    const int wave = threadIdx.x >> 6;
    if (lane == 0) wsum[wave] = s;
    __syncthreads();
    if (threadIdx.x == 0)
        out[0] = (wsum[0] + wsum[1] + wsum[2] + wsum[3]) * (1.0f / (float)BATCH);
}

extern "C" void kernel_launch(void* const* d_in, const int* in_sizes, int n_in,
                              void* d_out, int out_size, void* d_ws, size_t ws_size,
                              hipStream_t stream) {
    const float* pred = (const float*)d_in[0];
    const float* targ = (const float*)d_in[1];
    float* out = (float*)d_out;
    float* partial = (float*)d_ws;   // NBLOCKS floats = 12.5 KB scratch

    yolo_partial<<<NBLOCKS, BLOCK, 0, stream>>>(pred, targ, partial);
    yolo_final<<<1, BLOCK, 0, stream>>>(partial, out);
}

// Round 7
// 192.133 us; speedup vs baseline: 1.0488x; 1.0488x over previous
//
#include <hip/hip_runtime.h>

#define SDIM 14
#define L_COORD 5.0f
#define L_NOOBJ 0.5f
#define BATCH 4096
#define CELLS (BATCH * SDIM * SDIM)   // 802816
#define BLOCK 256
#define NBLOCKS (CELLS / BLOCK)       // 3136
#define CELL_F 30
#define BLK_F (BLOCK * CELL_F)        // 7680 floats per tensor per block
#define BLK_F4 (BLK_F / 4)            // 1920 float4 per tensor per block

typedef float f4v __attribute__((ext_vector_type(4)));

// Round-5 structure with ONE change: staging loads are inline-asm
// global_load_dwordx4 with sc0 sc1 nt (scope-coherent + non-temporal =
// bypass L1/TCP allocation&tracking). Theory from R0-R6: a single per-CU
// read-side server (~13.4 B/cyc/CU) upstream of the L3/HBM split caps all
// read structures at 2.6 (cached) / 3.45 (nt) TB/s; writes (no read-miss
// tracking) hit 6.8. If the server is the L1 miss path, sc0/sc1 bypass
// should unlock it. Explicit s_waitcnt vmcnt(0) before LDS writes because
// the compiler cannot track asm vmem counts (rule #18).
__global__ __launch_bounds__(BLOCK) void yolo_partial(
    const float* __restrict__ pred, const float* __restrict__ targ,
    float* __restrict__ partial) {
    // 60 KB LDS: [0, BLK_F) = pred cells, [BLK_F, 2*BLK_F) = targ cells
    __shared__ float s[2 * BLK_F];

    const size_t base = (size_t)blockIdx.x * BLK_F;
    const f4v* pP = reinterpret_cast<const f4v*>(pred + base);
    const f4v* pT = reinterpret_cast<const f4v*>(targ + base);
    f4v v[15];
#pragma unroll
    for (int j = 0; j < 15; ++j) {
        const int idx = threadIdx.x + j * BLOCK;  // 0..3839
        const f4v* src = (idx < BLK_F4) ? (pP + idx) : (pT + (idx - BLK_F4));
        asm volatile("global_load_dwordx4 %0, %1, off sc0 sc1 nt"
                     : "=v"(v[j]) : "v"(src));
    }
    // all 15 loads of this wave are in flight; drain once, then stage to LDS
    asm volatile("s_waitcnt vmcnt(0)" ::: "memory");
    f4v* s4 = reinterpret_cast<f4v*>(s);
#pragma unroll
    for (int j = 0; j < 15; ++j)
        s4[threadIdx.x + j * BLOCK] = v[j];
    __syncthreads();

    // ---- per-cell compute from LDS (verbatim rounds 0/5: absmax was 0) ----
    const float* Pc = s + threadIdx.x * CELL_F;
    const float* Tc = s + BLK_F + threadIdx.x * CELL_F;

    float loss;
    if (Tc[4] > 0.0f) {
        // class loss (channels 10..29)
        float cls = 0.0f;
#pragma unroll
        for (int c = 10; c < 30; ++c) { float d = Pc[c] - Tc[c]; cls += d * d; }

        const float invS = 1.0f / (float)SDIM;
        const float t1x = Tc[0] * invS - Tc[2] * 0.5f;
        const float t1y = Tc[1] * invS - Tc[3] * 0.5f;
        const float t2x = Tc[0] * invS + Tc[2] * 0.5f;
        const float t2y = Tc[1] * invS + Tc[3] * 0.5f;
        const float area_t = (t2x - t1x) * (t2y - t1y);

        float iou0 = 0.0f, iou1 = 0.0f;
#pragma unroll
        for (int k = 0; k < 2; ++k) {
            const float bx = Pc[5 * k + 0], by = Pc[5 * k + 1];
            const float bw = Pc[5 * k + 2], bh = Pc[5 * k + 3];
            const float p1x = bx * invS - bw * 0.5f;
            const float p1y = by * invS - bh * 0.5f;
            const float p2x = bx * invS + bw * 0.5f;
            const float p2y = by * invS + bh * 0.5f;
            const float ltx = fmaxf(p1x, t1x), lty = fmaxf(p1y, t1y);
            const float rbx = fminf(p2x, t2x), rby = fminf(p2y, t2y);
            const float wx = fmaxf(rbx - ltx, 0.0f);
            const float wy = fmaxf(rby - lty, 0.0f);
            const float inter = wx * wy;
            const float area_p = (p2x - p1x) * (p2y - p1y);
            const float v2 = inter / (area_p + area_t - inter);
            if (k == 0) iou0 = v2; else iou1 = v2;
        }

        const bool pick1 = (iou0 <= iou1);
        const float iou_best = pick1 ? iou1 : iou0;
        const float psx = pick1 ? Pc[5] : Pc[0];
        const float psy = pick1 ? Pc[6] : Pc[1];
        const float psw = pick1 ? Pc[7] : Pc[2];
        const float psh = pick1 ? Pc[8] : Pc[3];
        const float psc = pick1 ? Pc[9] : Pc[4];
        const float tsx = pick1 ? Tc[5] : Tc[0];
        const float tsy = pick1 ? Tc[6] : Tc[1];
        const float tsw = pick1 ? Tc[7] : Tc[2];
        const float tsh = pick1 ? Tc[8] : Tc[3];

        const float dx = psx - tsx, dy = psy - tsy;
        const float dw = sqrtf(psw) - sqrtf(tsw);
        const float dh = sqrtf(psh) - sqrtf(tsh);
        const float reg = dx * dx + dy * dy + dw * dw + dh * dh;
        const float dconf = psc - iou_best;
        loss = cls + L_COORD * reg + dconf * dconf;
    } else {
        const float d4 = Pc[4] - Tc[4];
        const float d9 = Pc[9] - Tc[9];
        loss = L_NOOBJ * (d4 * d4 + d9 * d9);
    }

    // ---- wave (64-lane) shuffle reduction ----
#pragma unroll
    for (int off = 32; off > 0; off >>= 1)
        loss += __shfl_down(loss, off, 64);

    __shared__ float wsum[BLOCK / 64];
    const int lane = threadIdx.x & 63;
    const int wave = threadIdx.x >> 6;
    if (lane == 0) wsum[wave] = loss;
    __syncthreads();
    if (threadIdx.x == 0)
        partial[blockIdx.x] = wsum[0] + wsum[1] + wsum[2] + wsum[3];
}

__global__ __launch_bounds__(BLOCK) void yolo_final(
    const float* __restrict__ partial, float* __restrict__ out) {
    float s = 0.0f;
    for (int i = threadIdx.x; i < NBLOCKS; i += BLOCK) s += partial[i];
#pragma unroll
    for (int off = 32; off > 0; off >>= 1)
        s += __shfl_down(s, off, 64);
    __shared__ float wsum[BLOCK / 64];
    const int lane = threadIdx.x & 63;
    const int wave = threadIdx.x >> 6;
    if (lane == 0) wsum[wave] = s;
    __syncthreads();
    if (threadIdx.x == 0)
        out[0] = (wsum[0] + wsum[1] + wsum[2] + wsum[3]) * (1.0f / (float)BATCH);
}

extern "C" void kernel_launch(void* const* d_in, const int* in_sizes, int n_in,
                              void* d_out, int out_size, void* d_ws, size_t ws_size,
                              hipStream_t stream) {
    const float* pred = (const float*)d_in[0];
    const float* targ = (const float*)d_in[1];
    float* out = (float*)d_out;
    float* partial = (float*)d_ws;   // NBLOCKS floats = 12.5 KB scratch

    yolo_partial<<<NBLOCKS, BLOCK, 0, stream>>>(pred, targ, partial);
    yolo_final<<<1, BLOCK, 0, stream>>>(partial, out);
}

// Round 8
// 191.900 us; speedup vs baseline: 1.0501x; 1.0012x over previous
//
#include <hip/hip_runtime.h>

#define SDIM 14
#define L_COORD 5.0f
#define L_NOOBJ 0.5f
#define BATCH 4096
#define CELLS (BATCH * SDIM * SDIM)   // 802816
#define BLOCK 256
#define NBLOCKS (CELLS / BLOCK)       // 3136
#define CELL_F 30
#define BLK_F (BLOCK * CELL_F)        // 7680 floats per tensor per block
#define BLK_F4 (BLK_F / 4)            // 1920 float4 per tensor per block

typedef float f4v __attribute__((ext_vector_type(4)));

// Round-5 structure with ONE change: staging uses global_load_lds dwordx4
// (TA->LDS direct DMA, NO VGPR writeback) with aux=2 (NT bit, R5's proven
// cache policy). Theory: the structure-invariant ~3.45 TB/s read cap may be
// the vector-return/VGPR-writeback path; global_load_lds is the only read
// path not yet tested. LDS dest = wave-uniform base + lane*16 -- our linear
// layout satisfies this exactly: byte(idx=tid+j*256) = 16*(64*wave+256*j)
// + 16*lane. If flat, the cap is upstream (request/L2 interface) and 3.45
// TB/s is the empirical read roofline.
__global__ __launch_bounds__(BLOCK) void yolo_partial(
    const float* __restrict__ pred, const float* __restrict__ targ,
    float* __restrict__ partial) {
    // 60 KB LDS: [0, BLK_F) = pred cells, [BLK_F, 2*BLK_F) = targ cells
    __shared__ float s[2 * BLK_F];

    const size_t base = (size_t)blockIdx.x * BLK_F;
    const f4v* pP = reinterpret_cast<const f4v*>(pred + base);
    const f4v* pT = reinterpret_cast<const f4v*>(targ + base);
    const int wavebase = threadIdx.x & ~63;   // lane-invariant per wave
#pragma unroll
    for (int j = 0; j < 15; ++j) {
        const int idx = threadIdx.x + j * BLOCK;  // per-lane global f4 index
        const f4v* src = (idx < BLK_F4) ? (pP + idx) : (pT + (idx - BLK_F4));
        // wave-uniform LDS base (floats): 4 * (wavebase + j*BLOCK); HW adds lane*16B
        float* ldst = s + 4 * (wavebase + j * BLOCK);
        __builtin_amdgcn_global_load_lds(
            (const __attribute__((address_space(1))) void*)src,
            (__attribute__((address_space(3))) void*)ldst,
            16, 0, 2 /* NT */);
    }
    // drain the DMA loads (compiler cannot fully track builtin vmem counts)
    asm volatile("s_waitcnt vmcnt(0)" ::: "memory");
    __syncthreads();

    // ---- per-cell compute from LDS (verbatim rounds 0/5: absmax was 0) ----
    const float* Pc = s + threadIdx.x * CELL_F;
    const float* Tc = s + BLK_F + threadIdx.x * CELL_F;

    float loss;
    if (Tc[4] > 0.0f) {
        // class loss (channels 10..29)
        float cls = 0.0f;
#pragma unroll
        for (int c = 10; c < 30; ++c) { float d = Pc[c] - Tc[c]; cls += d * d; }

        const float invS = 1.0f / (float)SDIM;
        const float t1x = Tc[0] * invS - Tc[2] * 0.5f;
        const float t1y = Tc[1] * invS - Tc[3] * 0.5f;
        const float t2x = Tc[0] * invS + Tc[2] * 0.5f;
        const float t2y = Tc[1] * invS + Tc[3] * 0.5f;
        const float area_t = (t2x - t1x) * (t2y - t1y);

        float iou0 = 0.0f, iou1 = 0.0f;
#pragma unroll
        for (int k = 0; k < 2; ++k) {
            const float bx = Pc[5 * k + 0], by = Pc[5 * k + 1];
            const float bw = Pc[5 * k + 2], bh = Pc[5 * k + 3];
            const float p1x = bx * invS - bw * 0.5f;
            const float p1y = by * invS - bh * 0.5f;
            const float p2x = bx * invS + bw * 0.5f;
            const float p2y = by * invS + bh * 0.5f;
            const float ltx = fmaxf(p1x, t1x), lty = fmaxf(p1y, t1y);
            const float rbx = fminf(p2x, t2x), rby = fminf(p2y, t2y);
            const float wx = fmaxf(rbx - ltx, 0.0f);
            const float wy = fmaxf(rby - lty, 0.0f);
            const float inter = wx * wy;
            const float area_p = (p2x - p1x) * (p2y - p1y);
            const float v2 = inter / (area_p + area_t - inter);
            if (k == 0) iou0 = v2; else iou1 = v2;
        }

        const bool pick1 = (iou0 <= iou1);
        const float iou_best = pick1 ? iou1 : iou0;
        const float psx = pick1 ? Pc[5] : Pc[0];
        const float psy = pick1 ? Pc[6] : Pc[1];
        const float psw = pick1 ? Pc[7] : Pc[2];
        const float psh = pick1 ? Pc[8] : Pc[3];
        const float psc = pick1 ? Pc[9] : Pc[4];
        const float tsx = pick1 ? Tc[5] : Tc[0];
        const float tsy = pick1 ? Tc[6] : Tc[1];
        const float tsw = pick1 ? Tc[7] : Tc[2];
        const float tsh = pick1 ? Tc[8] : Tc[3];

        const float dx = psx - tsx, dy = psy - tsy;
        const float dw = sqrtf(psw) - sqrtf(tsw);
        const float dh = sqrtf(psh) - sqrtf(tsh);
        const float reg = dx * dx + dy * dy + dw * dw + dh * dh;
        const float dconf = psc - iou_best;
        loss = cls + L_COORD * reg + dconf * dconf;
    } else {
        const float d4 = Pc[4] - Tc[4];
        const float d9 = Pc[9] - Tc[9];
        loss = L_NOOBJ * (d4 * d4 + d9 * d9);
    }

    // ---- wave (64-lane) shuffle reduction ----
#pragma unroll
    for (int off = 32; off > 0; off >>= 1)
        loss += __shfl_down(loss, off, 64);

    __shared__ float wsum[BLOCK / 64];
    const int lane = threadIdx.x & 63;
    const int wave = threadIdx.x >> 6;
    if (lane == 0) wsum[wave] = loss;
    __syncthreads();
    if (threadIdx.x == 0)
        partial[blockIdx.x] = wsum[0] + wsum[1] + wsum[2] + wsum[3];
}

__global__ __launch_bounds__(BLOCK) void yolo_final(
    const float* __restrict__ partial, float* __restrict__ out) {
    float s = 0.0f;
    for (int i = threadIdx.x; i < NBLOCKS; i += BLOCK) s += partial[i];
#pragma unroll
    for (int off = 32; off > 0; off >>= 1)
        s += __shfl_down(s, off, 64);
    __shared__ float wsum[BLOCK / 64];
    const int lane = threadIdx.x & 63;
    const int wave = threadIdx.x >> 6;
    if (lane == 0) wsum[wave] = s;
    __syncthreads();
    if (threadIdx.x == 0)
        out[0] = (wsum[0] + wsum[1] + wsum[2] + wsum[3]) * (1.0f / (float)BATCH);
}

extern "C" void kernel_launch(void* const* d_in, const int* in_sizes, int n_in,
                              void* d_out, int out_size, void* d_ws, size_t ws_size,
                              hipStream_t stream) {
    const float* pred = (const float*)d_in[0];
    const float* targ = (const float*)d_in[1];
    float* out = (float*)d_out;
    float* partial = (float*)d_ws;   // NBLOCKS floats = 12.5 KB scratch

    yolo_partial<<<NBLOCKS, BLOCK, 0, stream>>>(pred, targ, partial);
    yolo_final<<<1, BLOCK, 0, stream>>>(partial, out);
}